// Round 7
// baseline (254.920 us; speedup 1.0000x reference)
//
#include <hip/hip_runtime.h>

#define N_PTS 65536
#define BN_EPS 1e-5f
#define NSHD 16            // stat shadow copies

typedef __attribute__((ext_vector_type(8))) short bf16x8;
typedef __attribute__((ext_vector_type(4))) float f32x4;

static __device__ __forceinline__ unsigned short f2bf(float f) {
    unsigned u = __builtin_bit_cast(unsigned, f);
    u += 0x7fffu + ((u >> 16) & 1u);          // round-to-nearest-even
    return (unsigned short)(u >> 16);
}
static __device__ __forceinline__ float bf2f(unsigned short h) {
    unsigned u = ((unsigned)h) << 16;
    return __builtin_bit_cast(float, u);
}
static __device__ __forceinline__ unsigned pack2(float a, float b) {
    return (unsigned)f2bf(a) | ((unsigned)f2bf(b) << 16);
}

// ---------------------------------------------------------------------------
// split 8 weight matrices into bf16 hi/lo; slot = kind*2 + d, 4096 elems each
__global__ __launch_bounds__(256) void wconv_kernel(
    const float* __restrict__ fc1, const float* __restrict__ la1,
    const float* __restrict__ la2, const float* __restrict__ fc3,
    unsigned short* __restrict__ hi, unsigned short* __restrict__ lo)
{
    int i = blockIdx.x * 256 + threadIdx.x;   // 0..32767
    const float* p = (i < 8192) ? fc1 : (i < 16384) ? la1
                   : (i < 24576) ? la2 : fc3;
    float w = p[i & 8191];
    unsigned short h = f2bf(w);
    hi[i] = h;
    lo[i] = f2bf(w - bf2f(h));
}

// ---------------------------------------------------------------------------
// Fused (pre-op) -> 64x64 matmul (bf16x3 MFMA, ~fp32) -> (weighted) stats.
// Column-split: wave = 16 rows x 32 cols. Block = 4 waves = 32 rows x 64 cols.
// Grid = 2048 blocks. PRE: 0 none; 1 relu(bn(x)); 2 relu(id + bn(x)) -> f1_out.
template<int PRE, int BIAS, int WTD, int OUTBF, int HIST>
__global__ __launch_bounds__(256) void mm_kernel(
    const float* __restrict__ in,    const float* __restrict__ identity,
    const unsigned short* __restrict__ whi, const unsigned short* __restrict__ wlo,
    const float* __restrict__ bias,
    const float* __restrict__ gg,    const float* __restrict__ bb,
    const float* __restrict__ S_in,  float inv_denom,
    void*        __restrict__ outv,  float* __restrict__ S_out,
    const unsigned* __restrict__ cw, float* __restrict__ f1_out,
    const int* __restrict__ ref,     unsigned* __restrict__ hdst)
{
    __shared__ float sc[64], sh[64];
    __shared__ float LS[4][32], LQ[4][32];
    const int tid  = threadIdx.x;
    const int lane = tid & 63, wid = tid >> 6;
    const int l15  = lane & 15, kg = lane >> 4;
    const int rt   = wid >> 1, ch = wid & 1;       // row-tile, col-half
    const int brow = blockIdx.x * 32;
    const int arow = brow + rt * 16 + l15;

    // ---- early independent loads: issue before the BN prologue ----
    const float4* ap = (const float4*)(in + (size_t)arow * 64 + kg * 8);
    float4 a0 = ap[0], a1 = ap[1], a2 = ap[8], a3 = ap[9];

    bf16x8 wh[2][2], wl[2][2];
    #pragma unroll
    for (int ct = 0; ct < 2; ++ct) {
        const int gcol = ch * 32 + ct * 16 + l15;
        #pragma unroll
        for (int ks = 0; ks < 2; ++ks) {
            wh[ct][ks] = *(const bf16x8*)(whi + gcol * 64 + ks * 32 + kg * 8);
            wl[ct][ks] = *(const bf16x8*)(wlo + gcol * 64 + ks * 32 + kg * 8);
        }
    }
    float4 i0, i1, i2, i3;
    if (PRE == 2) {
        const float4* ip = (const float4*)(identity + (size_t)arow * 64 + kg * 8);
        i0 = ip[0]; i1 = ip[1]; i2 = ip[8]; i3 = ip[9];
    }
    float wt[4] = {1.f, 1.f, 1.f, 1.f};
    if (WTD) {
        #pragma unroll
        for (int i = 0; i < 4; ++i)
            wt[i] = (float)cw[brow + rt * 16 + kg * 4 + i];
    }
    if (HIST) {
        int2 hv = ((const int2*)(ref + brow * 16))[tid];
        atomicAdd(&hdst[hv.x], 1u); atomicAdd(&hdst[hv.y], 1u);
    }

    // ---- BN prologue: fold shadowed stats into scale/shift ----
    if (PRE >= 1) {
        if (tid < 64) {
            float s = 0.f, q = 0.f;
            #pragma unroll
            for (int g = 0; g < NSHD; ++g) {
                s += S_in[g * 128 + tid];
                q += S_in[g * 128 + 64 + tid];
            }
            float m   = s * inv_denom;
            float var = q * inv_denom - m * m;
            float scl = gg[tid] * rsqrtf(var + BN_EPS);
            sc[tid] = scl; sh[tid] = bb[tid] - m * scl;
        }
        __syncthreads();
    }

    float xv[2][8];
    xv[0][0]=a0.x; xv[0][1]=a0.y; xv[0][2]=a0.z; xv[0][3]=a0.w;
    xv[0][4]=a1.x; xv[0][5]=a1.y; xv[0][6]=a1.z; xv[0][7]=a1.w;
    xv[1][0]=a2.x; xv[1][1]=a2.y; xv[1][2]=a2.z; xv[1][3]=a2.w;
    xv[1][4]=a3.x; xv[1][5]=a3.y; xv[1][6]=a3.z; xv[1][7]=a3.w;

    if (PRE == 1) {
        #pragma unroll
        for (int ks = 0; ks < 2; ++ks)
            #pragma unroll
            for (int j = 0; j < 8; ++j) {
                int k = ks * 32 + kg * 8 + j;
                xv[ks][j] = fmaxf(xv[ks][j] * sc[k] + sh[k], 0.f);
            }
    } else if (PRE == 2) {
        float idv[2][8];
        idv[0][0]=i0.x; idv[0][1]=i0.y; idv[0][2]=i0.z; idv[0][3]=i0.w;
        idv[0][4]=i1.x; idv[0][5]=i1.y; idv[0][6]=i1.z; idv[0][7]=i1.w;
        idv[1][0]=i2.x; idv[1][1]=i2.y; idv[1][2]=i2.z; idv[1][3]=i2.w;
        idv[1][4]=i3.x; idv[1][5]=i3.y; idv[1][6]=i3.z; idv[1][7]=i3.w;
        #pragma unroll
        for (int ks = 0; ks < 2; ++ks) {
            #pragma unroll
            for (int j = 0; j < 8; ++j) {
                int k = ks * 32 + kg * 8 + j;
                xv[ks][j] = fmaxf(idv[ks][j] + xv[ks][j] * sc[k] + sh[k], 0.f);
            }
            if (ch == 0) {   // avoid duplicate writes from the two col-halves
                float* f1p = f1_out + (size_t)arow * 64 + kg * 8 + ks * 32;
                *(float4*)(f1p)     = make_float4(xv[ks][0], xv[ks][1], xv[ks][2], xv[ks][3]);
                *(float4*)(f1p + 4) = make_float4(xv[ks][4], xv[ks][5], xv[ks][6], xv[ks][7]);
            }
        }
    }

    // ---- split A into hi+lo bf16; MFMA D = Ahi@Whi + Alo@Whi + Ahi@Wlo ----
    bf16x8 ahi[2], alo[2];
    #pragma unroll
    for (int ks = 0; ks < 2; ++ks) {
        bf16x8 th, tl;
        #pragma unroll
        for (int j = 0; j < 8; ++j) {
            unsigned short h = f2bf(xv[ks][j]);
            th[j] = (short)h;
            tl[j] = (short)f2bf(xv[ks][j] - bf2f(h));
        }
        ahi[ks] = th; alo[ks] = tl;
    }
    f32x4 d[2];
    #pragma unroll
    for (int ct = 0; ct < 2; ++ct) {
        float bc = BIAS ? bias[ch * 32 + ct * 16 + l15] : 0.f;
        d[ct] = (f32x4){bc, bc, bc, bc};
    }
    #pragma unroll
    for (int ct = 0; ct < 2; ++ct)
        #pragma unroll
        for (int ks = 0; ks < 2; ++ks) {
            d[ct] = __builtin_amdgcn_mfma_f32_16x16x32_bf16(ahi[ks], wh[ct][ks], d[ct], 0, 0, 0);
            d[ct] = __builtin_amdgcn_mfma_f32_16x16x32_bf16(alo[ks], wh[ct][ks], d[ct], 0, 0, 0);
            d[ct] = __builtin_amdgcn_mfma_f32_16x16x32_bf16(ahi[ks], wl[ct][ks], d[ct], 0, 0, 0);
        }

    // ---- stats: D row = kg*4+i, col = ch*32 + ct*16 + l15 ----
    #pragma unroll
    for (int ct = 0; ct < 2; ++ct) {
        float t = 0.f, t2 = 0.f;
        #pragma unroll
        for (int i = 0; i < 4; ++i) {
            float v = d[ct][i];
            t += wt[i] * v; t2 += wt[i] * v * v;
        }
        t  += __shfl_xor(t, 16);  t  += __shfl_xor(t, 32);
        t2 += __shfl_xor(t2, 16); t2 += __shfl_xor(t2, 32);
        if (kg == 0) { LS[wid][ct * 16 + l15] = t; LQ[wid][ct * 16 + l15] = t2; }
    }
    __syncthreads();
    const int bsel = blockIdx.x & (NSHD - 1);
    if (tid < 64) {
        int ch2 = tid >> 5, cc = tid & 31;
        atomicAdd(S_out + bsel * 128 + tid,      LS[ch2][cc] + LS[2 + ch2][cc]);
        atomicAdd(S_out + bsel * 128 + 64 + tid, LQ[ch2][cc] + LQ[2 + ch2][cc]);
    }

    // ---- store ----
    if (!OUTBF) {
        float* op = (float*)outv;
        #pragma unroll
        for (int ct = 0; ct < 2; ++ct)
            #pragma unroll
            for (int i = 0; i < 4; ++i)
                op[(size_t)(brow + rt * 16 + kg * 4 + i) * 64 +
                   ch * 32 + ct * 16 + l15] = d[ct][i];
    } else {
        __shared__ float stg[4][16][33];
        #pragma unroll
        for (int ct = 0; ct < 2; ++ct)
            #pragma unroll
            for (int i = 0; i < 4; ++i)
                stg[wid][kg * 4 + i][ct * 16 + l15] = d[ct][i];
        __syncthreads();
        const float* srow = &stg[wid][l15][kg * 8];
        unsigned pk[4];
        #pragma unroll
        for (int q = 0; q < 4; ++q) pk[q] = pack2(srow[2 * q], srow[2 * q + 1]);
        unsigned* op = (unsigned*)outv;
        uint4* dst = (uint4*)(op + (size_t)(brow + rt * 16 + l15) * 32 + ch * 16 + kg * 4);
        *dst = make_uint4(pk[0], pk[1], pk[2], pk[3]);
    }
}

// ---------------------------------------------------------------------------
// xm[r,c] = relu(bn(max_k y3[ref[r,k],c])), y3 bf16-packed (u32 = 2 channels).
// half-wave = one row; one row-pair unit per wave; grid = 8192 blocks.
__global__ __launch_bounds__(256) void gather_kernel(
    const unsigned* __restrict__ y3u, const int* __restrict__ ref,
    const float* __restrict__ S_in, float inv_denom,
    const float* __restrict__ gg, const float* __restrict__ bb,
    float* __restrict__ xm, float* __restrict__ S_out)
{
    __shared__ float scs[64], shs[64], Rs[256], Rq[256];
    const int tid = threadIdx.x;
    const int lane = tid & 63, wid = tid >> 6;
    const int c2 = lane & 31;
    const int hsel = lane & 32;                 // 0 or 32 -> even/odd row
    const int p = blockIdx.x * 4 + wid;         // 0..32767
    const int r = 2 * p + (hsel ? 1 : 0);

    // issue gather loads BEFORE the BN prologue (latency hides under it)
    int jv = ref[r * 16 + (lane & 15)];
    unsigned u[16];
    #pragma unroll
    for (int t = 0; t < 16; ++t) {
        int j = __shfl(jv, hsel + t);
        u[t] = y3u[(size_t)j * 32 + c2];
    }

    if (tid < 64) {
        float s = 0.f, q = 0.f;
        #pragma unroll
        for (int g = 0; g < NSHD; ++g) {
            s += S_in[g * 128 + tid];
            q += S_in[g * 128 + 64 + tid];
        }
        float m   = s * inv_denom;
        float var = q * inv_denom - m * m;
        float scl = gg[tid] * rsqrtf(var + BN_EPS);
        scs[tid] = scl; shs[tid] = bb[tid] - m * scl;
    }
    __syncthreads();

    float m0 = bf2f((unsigned short)(u[0] & 0xffffu));
    float m1 = bf2f((unsigned short)(u[0] >> 16));
    #pragma unroll
    for (int t = 1; t < 16; ++t) {
        m0 = fmaxf(m0, bf2f((unsigned short)(u[t] & 0xffffu)));
        m1 = fmaxf(m1, bf2f((unsigned short)(u[t] >> 16)));
    }
    float x0 = fmaxf(m0 * scs[2*c2]   + shs[2*c2],   0.f);  // bn monotone
    float x1 = fmaxf(m1 * scs[2*c2+1] + shs[2*c2+1], 0.f);
    *(float2*)(xm + (size_t)r * 64 + 2 * c2) = make_float2(x0, x1);

    const int bsel = blockIdx.x & (NSHD - 1);
    Rs[tid] = x0; Rq[tid] = x0 * x0;
    __syncthreads();
    if (tid < 32) {
        float a = 0.f, c = 0.f;
        #pragma unroll
        for (int i = 0; i < 8; ++i) { a += Rs[tid + 32*i]; c += Rq[tid + 32*i]; }
        atomicAdd(S_out + bsel*128 + 2*tid, a);
        atomicAdd(S_out + bsel*128 + 64 + 2*tid, c);
    }
    __syncthreads();
    Rs[tid] = x1; Rq[tid] = x1 * x1;
    __syncthreads();
    if (tid < 32) {
        float a = 0.f, c = 0.f;
        #pragma unroll
        for (int i = 0; i < 8; ++i) { a += Rs[tid + 32*i]; c += Rq[tid + 32*i]; }
        atomicAdd(S_out + bsel*128 + 2*tid + 1, a);
        atomicAdd(S_out + bsel*128 + 64 + 2*tid + 1, c);
    }
}

// ---------------------------------------------------------------------------
// io = relu(io + y4*sc + sh)   (final residual, in place)
__global__ __launch_bounds__(256) void res_final(
    float* __restrict__ io, const float* __restrict__ y4,
    const float* __restrict__ S_in, float inv_denom,
    const float* __restrict__ gg, const float* __restrict__ bb)
{
    __shared__ float sc[64], sh[64];
    const int tid = threadIdx.x;
    int i = blockIdx.x * 256 + tid;            // float4 index
    float4 idv = ((const float4*)io)[i];
    float4 yv  = ((const float4*)y4)[i];
    if (tid < 64) {
        float s = 0.f, q = 0.f;
        #pragma unroll
        for (int g = 0; g < NSHD; ++g) {
            s += S_in[g * 128 + tid];
            q += S_in[g * 128 + 64 + tid];
        }
        float m   = s * inv_denom;
        float var = q * inv_denom - m * m;
        float scl = gg[tid] * rsqrtf(var + BN_EPS);
        sc[tid] = scl; sh[tid] = bb[tid] - m * scl;
    }
    __syncthreads();
    int c0 = (i * 4) & 63;
    float4 o;
    o.x = fmaxf(idv.x + yv.x * sc[c0+0] + sh[c0+0], 0.f);
    o.y = fmaxf(idv.y + yv.y * sc[c0+1] + sh[c0+1], 0.f);
    o.z = fmaxf(idv.z + yv.z * sc[c0+2] + sh[c0+2], 0.f);
    o.w = fmaxf(idv.w + yv.w * sc[c0+3] + sh[c0+3], 0.f);
    ((float4*)io)[i] = o;
}

// ---------------------------------------------------------------------------
extern "C" void kernel_launch(void* const* d_in, const int* in_sizes, int n_in,
                              void* d_out, int out_size, void* d_ws, size_t ws_size,
                              hipStream_t stream)
{
    const float* feat    = (const float*)d_in[1];
    const int*   ref     = (const int*)  d_in[2];
    const float* fc1_w   = (const float*)d_in[3];
    const float* bn1_g   = (const float*)d_in[4];
    const float* bn1_b   = (const float*)d_in[5];
    const float* la_w1   = (const float*)d_in[6];
    const float* la_b1   = (const float*)d_in[7];
    const float* la_bn1g = (const float*)d_in[8];
    const float* la_bn1b = (const float*)d_in[9];
    const float* la_w2   = (const float*)d_in[10];
    const float* la_b2   = (const float*)d_in[11];
    const float* la_bn2g = (const float*)d_in[12];
    const float* la_bn2b = (const float*)d_in[13];
    const float* fc3_w   = (const float*)d_in[14];
    const float* bn2_g   = (const float*)d_in[15];
    const float* bn2_b   = (const float*)d_in[16];
    const float* bn3_g   = (const float*)d_in[17];
    const float* bn3_b   = (const float*)d_in[18];
    float* out = (float*)d_out;

    // ws: R1 16MB | R2 16MB | cnt 256KB | Sb 80KB | Whi 64KB | Wlo 64KB
    char* base = (char*)d_ws;
    float*    R1  = (float*)base;
    float*    R2  = (float*)(base + 16u * 1024 * 1024);
    unsigned* cnt = (unsigned*)(base + 32u * 1024 * 1024);
    float*    Sb  = (float*)(cnt + N_PTS);
    unsigned short* Whi = (unsigned short*)(Sb + 10 * NSHD * 128);
    unsigned short* Wlo = Whi + 8 * 4096;
#define SS(i) (Sb + (i) * NSHD * 128)
#define WH(kind, d) (Whi + ((kind) * 2 + (d)) * 4096)
#define WL(kind, d) (Wlo + ((kind) * 2 + (d)) * 4096)

    hipMemsetAsync(cnt, 0,
        N_PTS * sizeof(unsigned) + 10 * NSHD * 128 * sizeof(float), stream);
    wconv_kernel<<<128, 256, 0, stream>>>(fc1_w, la_w1, la_w2, fc3_w, Whi, Wlo);

    const float invN  = 1.f / (float)N_PTS;
    const float invNK = invN / 16.f;
    const int MMG = N_PTS / 32;   // 2048 blocks

    // ---- block 0 ----
    mm_kernel<0,0,0,0,1><<<MMG,256,0,stream>>>(feat, nullptr, WH(0,0), WL(0,0),
        nullptr, nullptr, nullptr, nullptr, 0.f, R1, SS(0), nullptr, nullptr, ref, cnt);
    mm_kernel<1,1,1,0,0><<<MMG,256,0,stream>>>(R1, nullptr, WH(1,0), WL(1,0),
        la_b1, bn1_g, bn1_b, SS(0), invN, R2, SS(1), cnt, nullptr, nullptr, nullptr);
    mm_kernel<1,1,1,1,0><<<MMG,256,0,stream>>>(R2, nullptr, WH(2,0), WL(2,0),
        la_b2, la_bn1g, la_bn1b, SS(1), invNK, (void*)R1, SS(2), cnt, nullptr, nullptr, nullptr);
    gather_kernel<<<8192,256,0,stream>>>((const unsigned*)R1, ref, SS(2), invNK,
        la_bn2g, la_bn2b, R2, SS(3));
    mm_kernel<1,0,0,0,0><<<MMG,256,0,stream>>>(R2, nullptr, WH(3,0), WL(3,0),
        nullptr, bn2_g, bn2_b, SS(3), invN, R1, SS(4), nullptr, nullptr, nullptr, nullptr);

    // ---- block 1 (entry fuses block-0 residual; act0 -> out) ----
    mm_kernel<2,0,0,0,0><<<MMG,256,0,stream>>>(R1, feat, WH(0,1), WL(0,1),
        nullptr, bn3_g, bn3_b, SS(4), invN, R2, SS(5), nullptr, out, nullptr, nullptr);
    mm_kernel<1,1,1,0,0><<<MMG,256,0,stream>>>(R2, nullptr, WH(1,1), WL(1,1),
        la_b1 + 64, bn1_g + 64, bn1_b + 64, SS(5), invN, R1, SS(6), cnt, nullptr, nullptr, nullptr);
    mm_kernel<1,1,1,1,0><<<MMG,256,0,stream>>>(R1, nullptr, WH(2,1), WL(2,1),
        la_b2 + 64, la_bn1g + 64, la_bn1b + 64, SS(6), invNK, (void*)R2, SS(7), cnt, nullptr, nullptr, nullptr);
    gather_kernel<<<8192,256,0,stream>>>((const unsigned*)R2, ref, SS(7), invNK,
        la_bn2g + 64, la_bn2b + 64, R1, SS(8));
    mm_kernel<1,0,0,0,0><<<MMG,256,0,stream>>>(R1, nullptr, WH(3,1), WL(3,1),
        nullptr, bn2_g + 64, bn2_b + 64, SS(8), invN, R2, SS(9), nullptr, nullptr, nullptr, nullptr);
    res_final<<<(N_PTS * 64 / 4) / 256, 256, 0, stream>>>(out, R2, SS(9), invN,
        bn3_g + 64, bn3_b + 64);
}

// Round 9
// 220.297 us; speedup vs baseline: 1.1572x; 1.1572x over previous
//
#include <hip/hip_runtime.h>

#define N_PTS 65536
#define BN_EPS 1e-5f
#define NSHD 16            // stat shadow copies
#define NSB  (10 * NSHD * 128)

typedef __attribute__((ext_vector_type(8))) short bf16x8;
typedef __attribute__((ext_vector_type(4))) float f32x4;

static __device__ __forceinline__ unsigned short f2bf(float f) {
    unsigned u = __builtin_bit_cast(unsigned, f);
    u += 0x7fffu + ((u >> 16) & 1u);          // round-to-nearest-even
    return (unsigned short)(u >> 16);
}
static __device__ __forceinline__ float bf2f(unsigned short h) {
    unsigned u = ((unsigned)h) << 16;
    return __builtin_bit_cast(float, u);
}
static __device__ __forceinline__ unsigned pack2(float a, float b) {
    return (unsigned)f2bf(a) | ((unsigned)f2bf(b) << 16);
}

// ---------------------------------------------------------------------------
// split 8 weight matrices into bf16 hi/lo AND zero cnt + stats buffers.
__global__ __launch_bounds__(256) void wconv_kernel(
    const float* __restrict__ fc1, const float* __restrict__ la1,
    const float* __restrict__ la2, const float* __restrict__ fc3,
    unsigned short* __restrict__ hi, unsigned short* __restrict__ lo,
    unsigned* __restrict__ cnt, float* __restrict__ Sb)
{
    int i = blockIdx.x * 256 + threadIdx.x;   // 0..32767
    const float* p = (i < 8192) ? fc1 : (i < 16384) ? la1
                   : (i < 24576) ? la2 : fc3;
    float w = p[i & 8191];
    unsigned short h = f2bf(w);
    hi[i] = h;
    lo[i] = f2bf(w - bf2f(h));
    ((uint2*)cnt)[i] = make_uint2(0u, 0u);    // 65536 ints, 2 per thread
    if (i < NSB) Sb[i] = 0.f;
}

// ---------------------------------------------------------------------------
// Fused (pre-op) -> 64x64 matmul (bf16x3 MFMA, ~fp32) -> (weighted) stats.
// Wave = 16 rows x 64 cols, 2 row-tiles/wave. Block = 4 waves = 128 rows.
// Grid = 512. W staged in LDS (padded). All stores via LDS transpose.
template<int PRE, int BIAS, int WTD, int OUTBF, int HIST>
__global__ __launch_bounds__(256, 4) void mm_kernel(
    const float* __restrict__ in,    const float* __restrict__ identity,
    const unsigned short* __restrict__ whi, const unsigned short* __restrict__ wlo,
    const float* __restrict__ bias,
    const float* __restrict__ gg,    const float* __restrict__ bb,
    const float* __restrict__ S_in,  float inv_denom,
    void*        __restrict__ outv,  float* __restrict__ S_out,
    const unsigned* __restrict__ cw, float* __restrict__ f1_out,
    const int* __restrict__ ref,     unsigned* __restrict__ hdst)
{
    __shared__ unsigned short lwh[64][72], lwl[64][72];   // padded W rows
    __shared__ float stg[4][16][68];
    __shared__ float sc[64], sh[64];
    __shared__ float LS[4][64], LQ[4][64];

    const int tid  = threadIdx.x;
    const int lane = tid & 63, wid = tid >> 6;
    const int l15  = lane & 15, kg = lane >> 4;
    const int brow = blockIdx.x * 128;
    const int r0   = brow + wid * 16;          // tile0 rows r0..r0+15
    const int r1   = r0 + 64;                  // tile1

    // ---- issue ALL independent global loads up front ----
    // W fill: 4096 shorts / 256 threads = 16 shorts (2 x uint4) per thread:
    // 4 threads per 64-short row.
    const int wrow = tid >> 2, wcol = (tid & 3) * 16;
    const uint4* wsh = (const uint4*)(whi + wrow * 64 + wcol);
    const uint4* wsl = (const uint4*)(wlo + wrow * 64 + wcol);
    uint4 wf0 = wsh[0], wf1 = wsh[1], wf2 = wsl[0], wf3 = wsl[1];

    const float4* ap0 = (const float4*)(in + (size_t)(r0 + l15) * 64 + kg * 8);
    const float4* ap1 = (const float4*)(in + (size_t)(r1 + l15) * 64 + kg * 8);
    float4 a00 = ap0[0], a01 = ap0[1], a02 = ap0[8], a03 = ap0[9];
    float4 a10 = ap1[0], a11 = ap1[1], a12 = ap1[8], a13 = ap1[9];

    float4 i00, i01, i02, i03, i10, i11, i12, i13;
    if (PRE == 2) {
        const float4* ip0 = (const float4*)(identity + (size_t)(r0 + l15) * 64 + kg * 8);
        const float4* ip1 = (const float4*)(identity + (size_t)(r1 + l15) * 64 + kg * 8);
        i00 = ip0[0]; i01 = ip0[1]; i02 = ip0[8]; i03 = ip0[9];
        i10 = ip1[0]; i11 = ip1[1]; i12 = ip1[8]; i13 = ip1[9];
    }
    uint4 c0, c1;
    if (WTD) {
        c0 = ((const uint4*)(cw + r0))[kg];
        c1 = ((const uint4*)(cw + r1))[kg];
    }
    if (HIST) {
        const int4* rp = (const int4*)(ref + brow * 16) + tid * 2;
        int4 h0 = rp[0], h1 = rp[1];
        atomicAdd(&hdst[h0.x], 1u); atomicAdd(&hdst[h0.y], 1u);
        atomicAdd(&hdst[h0.z], 1u); atomicAdd(&hdst[h0.w], 1u);
        atomicAdd(&hdst[h1.x], 1u); atomicAdd(&hdst[h1.y], 1u);
        atomicAdd(&hdst[h1.z], 1u); atomicAdd(&hdst[h1.w], 1u);
    }

    // ---- W -> LDS ----
    {
        uint4* dh = (uint4*)(&lwh[wrow][wcol]);
        uint4* dl = (uint4*)(&lwl[wrow][wcol]);
        dh[0] = wf0; dh[1] = wf1; dl[0] = wf2; dl[1] = wf3;
    }

    // ---- BN prologue ----
    if (PRE >= 1) {
        if (tid < 64) {
            float s = 0.f, q = 0.f;
            #pragma unroll
            for (int g = 0; g < NSHD; ++g) {
                s += S_in[g * 128 + tid];
                q += S_in[g * 128 + 64 + tid];
            }
            float m   = s * inv_denom;
            float var = q * inv_denom - m * m;
            float scl = gg[tid] * rsqrtf(var + BN_EPS);
            sc[tid] = scl; sh[tid] = bb[tid] - m * scl;
        }
    }
    __syncthreads();

    float ts[4] = {0.f, 0.f, 0.f, 0.f}, tq[4] = {0.f, 0.f, 0.f, 0.f};

    #pragma unroll
    for (int t = 0; t < 2; ++t) {
        const int rr = t ? r1 : r0;
        float xv[2][8];
        if (t == 0) {
            xv[0][0]=a00.x; xv[0][1]=a00.y; xv[0][2]=a00.z; xv[0][3]=a00.w;
            xv[0][4]=a01.x; xv[0][5]=a01.y; xv[0][6]=a01.z; xv[0][7]=a01.w;
            xv[1][0]=a02.x; xv[1][1]=a02.y; xv[1][2]=a02.z; xv[1][3]=a02.w;
            xv[1][4]=a03.x; xv[1][5]=a03.y; xv[1][6]=a03.z; xv[1][7]=a03.w;
        } else {
            xv[0][0]=a10.x; xv[0][1]=a10.y; xv[0][2]=a10.z; xv[0][3]=a10.w;
            xv[0][4]=a11.x; xv[0][5]=a11.y; xv[0][6]=a11.z; xv[0][7]=a11.w;
            xv[1][0]=a12.x; xv[1][1]=a12.y; xv[1][2]=a12.z; xv[1][3]=a12.w;
            xv[1][4]=a13.x; xv[1][5]=a13.y; xv[1][6]=a13.z; xv[1][7]=a13.w;
        }
        if (PRE == 1) {
            #pragma unroll
            for (int ks = 0; ks < 2; ++ks)
                #pragma unroll
                for (int j = 0; j < 8; ++j) {
                    int k = ks * 32 + kg * 8 + j;
                    xv[ks][j] = fmaxf(xv[ks][j] * sc[k] + sh[k], 0.f);
                }
        } else if (PRE == 2) {
            float idv[2][8];
            if (t == 0) {
                idv[0][0]=i00.x; idv[0][1]=i00.y; idv[0][2]=i00.z; idv[0][3]=i00.w;
                idv[0][4]=i01.x; idv[0][5]=i01.y; idv[0][6]=i01.z; idv[0][7]=i01.w;
                idv[1][0]=i02.x; idv[1][1]=i02.y; idv[1][2]=i02.z; idv[1][3]=i02.w;
                idv[1][4]=i03.x; idv[1][5]=i03.y; idv[1][6]=i03.z; idv[1][7]=i03.w;
            } else {
                idv[0][0]=i10.x; idv[0][1]=i10.y; idv[0][2]=i10.z; idv[0][3]=i10.w;
                idv[0][4]=i11.x; idv[0][5]=i11.y; idv[0][6]=i11.z; idv[0][7]=i11.w;
                idv[1][0]=i12.x; idv[1][1]=i12.y; idv[1][2]=i12.z; idv[1][3]=i12.w;
                idv[1][4]=i13.x; idv[1][5]=i13.y; idv[1][6]=i13.z; idv[1][7]=i13.w;
            }
            #pragma unroll
            for (int ks = 0; ks < 2; ++ks) {
                #pragma unroll
                for (int j = 0; j < 8; ++j) {
                    int k = ks * 32 + kg * 8 + j;
                    xv[ks][j] = fmaxf(idv[ks][j] + xv[ks][j] * sc[k] + sh[k], 0.f);
                }
                float* f1p = f1_out + (size_t)(rr + l15) * 64 + kg * 8 + ks * 32;
                *(float4*)(f1p)     = make_float4(xv[ks][0], xv[ks][1], xv[ks][2], xv[ks][3]);
                *(float4*)(f1p + 4) = make_float4(xv[ks][4], xv[ks][5], xv[ks][6], xv[ks][7]);
            }
        }

        // split A into hi+lo bf16
        bf16x8 ahi[2], alo[2];
        #pragma unroll
        for (int ks = 0; ks < 2; ++ks) {
            bf16x8 th, tl;
            #pragma unroll
            for (int j = 0; j < 8; ++j) {
                unsigned short h = f2bf(xv[ks][j]);
                th[j] = (short)h;
                tl[j] = (short)f2bf(xv[ks][j] - bf2f(h));
            }
            ahi[ks] = th; alo[ks] = tl;
        }
        f32x4 d[4];
        #pragma unroll
        for (int ct = 0; ct < 4; ++ct) {
            float bc = BIAS ? bias[ct * 16 + l15] : 0.f;
            d[ct] = (f32x4){bc, bc, bc, bc};
        }
        #pragma unroll
        for (int ct = 0; ct < 4; ++ct) {
            const int gcol = ct * 16 + l15;
            #pragma unroll
            for (int ks = 0; ks < 2; ++ks) {
                bf16x8 wh = *(const bf16x8*)(&lwh[gcol][ks * 32 + kg * 8]);
                bf16x8 wl = *(const bf16x8*)(&lwl[gcol][ks * 32 + kg * 8]);
                d[ct] = __builtin_amdgcn_mfma_f32_16x16x32_bf16(ahi[ks], wh, d[ct], 0, 0, 0);
                d[ct] = __builtin_amdgcn_mfma_f32_16x16x32_bf16(alo[ks], wh, d[ct], 0, 0, 0);
                d[ct] = __builtin_amdgcn_mfma_f32_16x16x32_bf16(ahi[ks], wl, d[ct], 0, 0, 0);
            }
        }

        // stats partial (weighted per tile-row)
        float wt[4] = {1.f, 1.f, 1.f, 1.f};
        if (WTD) {
            uint4 cc = t ? c1 : c0;
            wt[0] = (float)cc.x; wt[1] = (float)cc.y;
            wt[2] = (float)cc.z; wt[3] = (float)cc.w;
        }
        #pragma unroll
        for (int ct = 0; ct < 4; ++ct) {
            #pragma unroll
            for (int i = 0; i < 4; ++i) {
                float v = d[ct][i];
                ts[ct] += wt[i] * v; tq[ct] += wt[i] * v * v;
            }
        }

        // store via per-wave LDS transpose
        #pragma unroll
        for (int ct = 0; ct < 4; ++ct)
            #pragma unroll
            for (int i = 0; i < 4; ++i)
                stg[wid][kg * 4 + i][ct * 16 + l15] = d[ct][i];
        __syncthreads();
        if (!OUTBF) {
            float* op = (float*)outv + (size_t)(rr + l15) * 64 + kg * 16;
            const float* srow = &stg[wid][l15][kg * 16];
            *(float4*)(op + 0)  = *(const float4*)(srow + 0);
            *(float4*)(op + 4)  = *(const float4*)(srow + 4);
            *(float4*)(op + 8)  = *(const float4*)(srow + 8);
            *(float4*)(op + 12) = *(const float4*)(srow + 12);
        } else {
            const float* srow = &stg[wid][l15][kg * 16];
            unsigned pk[8];
            #pragma unroll
            for (int q = 0; q < 8; ++q) pk[q] = pack2(srow[2 * q], srow[2 * q + 1]);
            unsigned* op = (unsigned*)outv;
            uint4* dst = (uint4*)(op + (size_t)(rr + l15) * 32 + kg * 8);
            dst[0] = make_uint4(pk[0], pk[1], pk[2], pk[3]);
            dst[1] = make_uint4(pk[4], pk[5], pk[6], pk[7]);
        }
        __syncthreads();     // stg reads done before next tile overwrites
    }

    // ---- cross-wave stats reduce + atomics ----
    #pragma unroll
    for (int ct = 0; ct < 4; ++ct) {
        float a = ts[ct], b = tq[ct];
        a += __shfl_xor(a, 16);  a += __shfl_xor(a, 32);
        b += __shfl_xor(b, 16);  b += __shfl_xor(b, 32);
        if (kg == 0) { LS[wid][ct * 16 + l15] = a; LQ[wid][ct * 16 + l15] = b; }
    }
    __syncthreads();
    const int bsel = blockIdx.x & (NSHD - 1);
    if (tid < 64)
        atomicAdd(S_out + bsel * 128 + tid,
                  LS[0][tid] + LS[1][tid] + LS[2][tid] + LS[3][tid]);
    else if (tid < 128) {
        int c = tid - 64;
        atomicAdd(S_out + bsel * 128 + 64 + c,
                  LQ[0][c] + LQ[1][c] + LQ[2][c] + LQ[3][c]);
    }
}

// ---------------------------------------------------------------------------
// xm[r,c] = relu(bn(max_k y3[ref[r,k],c])), y3 bf16-packed (u32 = 2 channels).
// half-wave = one row; loads issued before the BN prologue. grid = 8192.
__global__ __launch_bounds__(256) void gather_kernel(
    const unsigned* __restrict__ y3u, const int* __restrict__ ref,
    const float* __restrict__ S_in, float inv_denom,
    const float* __restrict__ gg, const float* __restrict__ bb,
    float* __restrict__ xm, float* __restrict__ S_out)
{
    __shared__ float scs[64], shs[64], Rs[256], Rq[256];
    const int tid = threadIdx.x;
    const int lane = tid & 63, wid = tid >> 6;
    const int c2 = lane & 31;
    const int hsel = lane & 32;                 // 0 or 32 -> even/odd row
    const int p = blockIdx.x * 4 + wid;         // 0..32767
    const int r = 2 * p + (hsel ? 1 : 0);

    int jv = ref[r * 16 + (lane & 15)];
    unsigned u[16];
    #pragma unroll
    for (int t = 0; t < 16; ++t) {
        int j = __shfl(jv, hsel + t);
        u[t] = y3u[(size_t)j * 32 + c2];
    }

    if (tid < 64) {
        float s = 0.f, q = 0.f;
        #pragma unroll
        for (int g = 0; g < NSHD; ++g) {
            s += S_in[g * 128 + tid];
            q += S_in[g * 128 + 64 + tid];
        }
        float m   = s * inv_denom;
        float var = q * inv_denom - m * m;
        float scl = gg[tid] * rsqrtf(var + BN_EPS);
        scs[tid] = scl; shs[tid] = bb[tid] - m * scl;
    }
    __syncthreads();

    float m0 = bf2f((unsigned short)(u[0] & 0xffffu));
    float m1 = bf2f((unsigned short)(u[0] >> 16));
    #pragma unroll
    for (int t = 1; t < 16; ++t) {
        m0 = fmaxf(m0, bf2f((unsigned short)(u[t] & 0xffffu)));
        m1 = fmaxf(m1, bf2f((unsigned short)(u[t] >> 16)));
    }
    float x0 = fmaxf(m0 * scs[2*c2]   + shs[2*c2],   0.f);  // bn monotone
    float x1 = fmaxf(m1 * scs[2*c2+1] + shs[2*c2+1], 0.f);
    *(float2*)(xm + (size_t)r * 64 + 2 * c2) = make_float2(x0, x1);

    const int bsel = blockIdx.x & (NSHD - 1);
    Rs[tid] = x0; Rq[tid] = x0 * x0;
    __syncthreads();
    if (tid < 32) {
        float a = 0.f, c = 0.f;
        #pragma unroll
        for (int i = 0; i < 8; ++i) { a += Rs[tid + 32*i]; c += Rq[tid + 32*i]; }
        atomicAdd(S_out + bsel*128 + 2*tid, a);
        atomicAdd(S_out + bsel*128 + 64 + 2*tid, c);
    }
    __syncthreads();
    Rs[tid] = x1; Rq[tid] = x1 * x1;
    __syncthreads();
    if (tid < 32) {
        float a = 0.f, c = 0.f;
        #pragma unroll
        for (int i = 0; i < 8; ++i) { a += Rs[tid + 32*i]; c += Rq[tid + 32*i]; }
        atomicAdd(S_out + bsel*128 + 2*tid + 1, a);
        atomicAdd(S_out + bsel*128 + 64 + 2*tid + 1, c);
    }
}

// ---------------------------------------------------------------------------
// io = relu(io + y4*sc + sh)   (final residual, in place)
__global__ __launch_bounds__(256) void res_final(
    float* __restrict__ io, const float* __restrict__ y4,
    const float* __restrict__ S_in, float inv_denom,
    const float* __restrict__ gg, const float* __restrict__ bb)
{
    __shared__ float sc[64], sh[64];
    const int tid = threadIdx.x;
    int i = blockIdx.x * 256 + tid;            // float4 index
    float4 idv = ((const float4*)io)[i];
    float4 yv  = ((const float4*)y4)[i];
    if (tid < 64) {
        float s = 0.f, q = 0.f;
        #pragma unroll
        for (int g = 0; g < NSHD; ++g) {
            s += S_in[g * 128 + tid];
            q += S_in[g * 128 + 64 + tid];
        }
        float m   = s * inv_denom;
        float var = q * inv_denom - m * m;
        float scl = gg[tid] * rsqrtf(var + BN_EPS);
        sc[tid] = scl; sh[tid] = bb[tid] - m * scl;
    }
    __syncthreads();
    int c0 = (i * 4) & 63;
    float4 o;
    o.x = fmaxf(idv.x + yv.x * sc[c0+0] + sh[c0+0], 0.f);
    o.y = fmaxf(idv.y + yv.y * sc[c0+1] + sh[c0+1], 0.f);
    o.z = fmaxf(idv.z + yv.z * sc[c0+2] + sh[c0+2], 0.f);
    o.w = fmaxf(idv.w + yv.w * sc[c0+3] + sh[c0+3], 0.f);
    ((float4*)io)[i] = o;
}

// ---------------------------------------------------------------------------
extern "C" void kernel_launch(void* const* d_in, const int* in_sizes, int n_in,
                              void* d_out, int out_size, void* d_ws, size_t ws_size,
                              hipStream_t stream)
{
    const float* feat    = (const float*)d_in[1];
    const int*   ref     = (const int*)  d_in[2];
    const float* fc1_w   = (const float*)d_in[3];
    const float* bn1_g   = (const float*)d_in[4];
    const float* bn1_b   = (const float*)d_in[5];
    const float* la_w1   = (const float*)d_in[6];
    const float* la_b1   = (const float*)d_in[7];
    const float* la_bn1g = (const float*)d_in[8];
    const float* la_bn1b = (const float*)d_in[9];
    const float* la_w2   = (const float*)d_in[10];
    const float* la_b2   = (const float*)d_in[11];
    const float* la_bn2g = (const float*)d_in[12];
    const float* la_bn2b = (const float*)d_in[13];
    const float* fc3_w   = (const float*)d_in[14];
    const float* bn2_g   = (const float*)d_in[15];
    const float* bn2_b   = (const float*)d_in[16];
    const float* bn3_g   = (const float*)d_in[17];
    const float* bn3_b   = (const float*)d_in[18];
    float* out = (float*)d_out;

    // ws: R1 16MB | R2 16MB | cnt 256KB | Sb 80KB | Whi 64KB | Wlo 64KB
    char* base = (char*)d_ws;
    float*    R1  = (float*)base;
    float*    R2  = (float*)(base + 16u * 1024 * 1024);
    unsigned* cnt = (unsigned*)(base + 32u * 1024 * 1024);
    float*    Sb  = (float*)(cnt + N_PTS);
    unsigned short* Whi = (unsigned short*)(Sb + NSB);
    unsigned short* Wlo = Whi + 8 * 4096;
#define SS(i) (Sb + (i) * NSHD * 128)
#define WH(kind, d) (Whi + ((kind) * 2 + (d)) * 4096)
#define WL(kind, d) (Wlo + ((kind) * 2 + (d)) * 4096)

    wconv_kernel<<<128, 256, 0, stream>>>(fc1_w, la_w1, la_w2, fc3_w,
                                          Whi, Wlo, cnt, Sb);

    const float invN  = 1.f / (float)N_PTS;
    const float invNK = invN / 16.f;
    const int MMG = N_PTS / 128;   // 512 blocks

    // ---- block 0 ----
    mm_kernel<0,0,0,0,1><<<MMG,256,0,stream>>>(feat, nullptr, WH(0,0), WL(0,0),
        nullptr, nullptr, nullptr, nullptr, 0.f, R1, SS(0), nullptr, nullptr, ref, cnt);
    mm_kernel<1,1,1,0,0><<<MMG,256,0,stream>>>(R1, nullptr, WH(1,0), WL(1,0),
        la_b1, bn1_g, bn1_b, SS(0), invN, R2, SS(1), cnt, nullptr, nullptr, nullptr);
    mm_kernel<1,1,1,1,0><<<MMG,256,0,stream>>>(R2, nullptr, WH(2,0), WL(2,0),
        la_b2, la_bn1g, la_bn1b, SS(1), invNK, (void*)R1, SS(2), cnt, nullptr, nullptr, nullptr);
    gather_kernel<<<8192,256,0,stream>>>((const unsigned*)R1, ref, SS(2), invNK,
        la_bn2g, la_bn2b, R2, SS(3));
    mm_kernel<1,0,0,0,0><<<MMG,256,0,stream>>>(R2, nullptr, WH(3,0), WL(3,0),
        nullptr, bn2_g, bn2_b, SS(3), invN, R1, SS(4), nullptr, nullptr, nullptr, nullptr);

    // ---- block 1 (entry fuses block-0 residual; act0 -> out) ----
    mm_kernel<2,0,0,0,0><<<MMG,256,0,stream>>>(R1, feat, WH(0,1), WL(0,1),
        nullptr, bn3_g, bn3_b, SS(4), invN, R2, SS(5), nullptr, out, nullptr, nullptr);
    mm_kernel<1,1,1,0,0><<<MMG,256,0,stream>>>(R2, nullptr, WH(1,1), WL(1,1),
        la_b1 + 64, bn1_g + 64, bn1_b + 64, SS(5), invN, R1, SS(6), cnt, nullptr, nullptr, nullptr);
    mm_kernel<1,1,1,1,0><<<MMG,256,0,stream>>>(R1, nullptr, WH(2,1), WL(2,1),
        la_b2 + 64, la_bn1g + 64, la_bn1b + 64, SS(6), invNK, (void*)R2, SS(7), cnt, nullptr, nullptr, nullptr);
    gather_kernel<<<8192,256,0,stream>>>((const unsigned*)R2, ref, SS(7), invNK,
        la_bn2g + 64, la_bn2b + 64, R1, SS(8));
    mm_kernel<1,0,0,0,0><<<MMG,256,0,stream>>>(R1, nullptr, WH(3,1), WL(3,1),
        nullptr, bn2_g + 64, bn2_b + 64, SS(8), invN, R2, SS(9), nullptr, nullptr, nullptr, nullptr);
    res_final<<<(N_PTS * 64 / 4) / 256, 256, 0, stream>>>(out, R2, SS(9), invN,
        bn3_g + 64, bn3_b + 64);
}